// Round 6
// baseline (452.810 us; speedup 1.0000x reference)
//
#include <hip/hip_runtime.h>
#include <hip/hip_bf16.h>

typedef __bf16 bf16x8 __attribute__((ext_vector_type(8)));
typedef __bf16 bf16x4 __attribute__((ext_vector_type(4)));
typedef float  f32x4  __attribute__((ext_vector_type(4)));

#define T_TOK    8192
#define D_DIM    1024
#define H_DIM    2048
#define E_NUM    8
#define MAX_MB   136      // 17*8; sum ceil(n_e/128) <= 8 + 16384/128 = 136
#define MAX_ROWS 17408    // 136*128

// ---- workspace layout (bytes) ----
#define OFF_MBTOT   512
#define OFF_MB2E    1024
#define OFF_MBROW0  2048
#define OFF_TOPKE   4096            // 16384 ints  -> ends 69632
#define OFF_TOPKS   69632           // 16384 float -> ends 135168
#define OFF_TOK     135168          // 17408 ints  -> ends 204800
#define OFF_ROWIDX  204800          // 16384 ints  -> ends 270336
#define OFF_XB      (1u<<20)                    // 8192*1024*2  = 16 MiB
#define OFF_W1T     (18u*1024*1024)             // 8*2048*1024*2 = 32 MiB -> ends 50 MiB
#define OFF_W2T     (50u*1024*1024)             // 8*1024*2048*2 = 32 MiB -> ends 82 MiB
#define OFF_HBUF    (82u*1024*1024)             // 17408*2048*2  = 68 MiB -> ends 150 MiB
// ybuf bf16 [17408][1024] = 34 MiB overlaid on xb+W1T (both dead after gemm1)
#define OFF_YBUF    OFF_XB

__device__ __forceinline__ void gload_lds16(const void* g, void* l) {
    __builtin_amdgcn_global_load_lds(
        (const __attribute__((address_space(1))) void*)g,
        (__attribute__((address_space(3))) void*)l, 16, 0, 0);
}

// ---------------- fused router (+ fp32->bf16 convert of x) ----------------
// No LDS, no atomics: Wg (32 KB) read directly from global -> L1-resident.
__global__ __launch_bounds__(256) void k_router_cvt(
    const float* __restrict__ x, const float* __restrict__ Wg,
    __bf16* __restrict__ xb, int* __restrict__ topk_e, float* __restrict__ topk_s)
{
    const int tid = threadIdx.x;
    const int wave = tid >> 6, lane = tid & 63;
    const int t = blockIdx.x * 4 + wave;
    const float* xr = x + (size_t)t * D_DIM;
    __bf16* xbr = xb + (size_t)t * D_DIM;

    float acc[E_NUM];
#pragma unroll
    for (int e = 0; e < E_NUM; ++e) acc[e] = 0.f;

#pragma unroll
    for (int j = 0; j < 4; ++j) {
        const int d0 = lane * 4 + j * 256;
        float4 xv = *(const float4*)(xr + d0);
        bf16x4 o = { (__bf16)xv.x, (__bf16)xv.y, (__bf16)xv.z, (__bf16)xv.w };
        *(bf16x4*)(xbr + d0) = o;
        const float* xvf = (const float*)&xv;
#pragma unroll
        for (int u = 0; u < 4; ++u) {
            float4 wlo = *(const float4*)(Wg + (size_t)(d0 + u) * E_NUM);
            float4 whi = *(const float4*)(Wg + (size_t)(d0 + u) * E_NUM + 4);
            float xd = xvf[u];
            acc[0] += xd * wlo.x; acc[1] += xd * wlo.y;
            acc[2] += xd * wlo.z; acc[3] += xd * wlo.w;
            acc[4] += xd * whi.x; acc[5] += xd * whi.y;
            acc[6] += xd * whi.z; acc[7] += xd * whi.w;
        }
    }
#pragma unroll
    for (int off = 32; off >= 1; off >>= 1)
#pragma unroll
        for (int e = 0; e < E_NUM; ++e) acc[e] += __shfl_xor(acc[e], off, 64);

    if (lane == 0) {
        int e0 = 0; float v0 = acc[0];
#pragma unroll
        for (int e = 1; e < E_NUM; ++e) if (acc[e] > v0) { v0 = acc[e]; e0 = e; }
        int e1 = -1; float v1 = -1e30f;
#pragma unroll
        for (int e = 0; e < E_NUM; ++e) if (e != e0 && acc[e] > v1) { v1 = acc[e]; e1 = e; }
        float s0 = 1.f / (1.f + __expf(v1 - v0));  // renormalized top-2 softmax
        float s1 = 1.f - s0;
        topk_e[t*2+0] = e0; topk_e[t*2+1] = e1;
        topk_s[t*2+0] = s0; topk_s[t*2+1] = s1;
    }
}

// ---------------- single-block counting sort (LDS counters, no scratch) ----------------
#define SORT_T 256
__global__ __launch_bounds__(512) void k_sort(
    const int* __restrict__ topk_e,
    int* __restrict__ mbTot, int* __restrict__ mb2e, int* __restrict__ mbrow0,
    int* __restrict__ tok, int* __restrict__ rowidx)
{
    __shared__ int lcnt[E_NUM][SORT_T];
    __shared__ int base[E_NUM];
    __shared__ int etot[E_NUM];
    const int tid = threadIdx.x;

    if (tid < SORT_T) {
#pragma unroll
        for (int e = 0; e < E_NUM; ++e) lcnt[e][tid] = 0;
    }
    __syncthreads();

    if (tid < SORT_T) {
        const int4* p = (const int4*)(topk_e + tid * 64);
#pragma unroll
        for (int i = 0; i < 16; ++i) {
            int4 v = p[i];
            lcnt[v.x][tid]++; lcnt[v.y][tid]++; lcnt[v.z][tid]++; lcnt[v.w][tid]++;
        }
    }
    __syncthreads();

    {
        const int w = tid >> 6, l = tid & 63;
        int v0 = lcnt[w][l*4+0], v1 = lcnt[w][l*4+1], v2 = lcnt[w][l*4+2], v3 = lcnt[w][l*4+3];
        int s = v0 + v1 + v2 + v3;
        int inc = s;
#pragma unroll
        for (int off = 1; off < 64; off <<= 1) {
            int o = __shfl_up(inc, off, 64);
            if (l >= off) inc += o;
        }
        int exc = inc - s;
        lcnt[w][l*4+0] = exc;
        lcnt[w][l*4+1] = exc + v0;
        lcnt[w][l*4+2] = exc + v0 + v1;
        lcnt[w][l*4+3] = exc + v0 + v1 + v2;
        if (l == 63) etot[w] = inc;
    }
    __syncthreads();

    if (tid == 0) {
        int row = 0, mb = 0;
        for (int e = 0; e < E_NUM; ++e) {
            base[e] = row;
            int nb = (etot[e] + 127) >> 7;
            for (int b = 0; b < nb; ++b) { mb2e[mb] = e; mbrow0[mb] = row + b*128; ++mb; }
            row += nb * 128;
        }
        mbTot[0] = mb;
    }
    __syncthreads();

    if (tid < SORT_T) {
#pragma unroll
        for (int e = 0; e < E_NUM; ++e) lcnt[e][tid] += base[e];
        const int4* p = (const int4*)(topk_e + tid * 64);
#pragma unroll
        for (int i = 0; i < 16; ++i) {
            int4 v = p[i];
            int j0 = tid * 64 + i * 4;
            int r;
            r = lcnt[v.x][tid]++; tok[r] = (j0+0) >> 1; rowidx[j0+0] = r;
            r = lcnt[v.y][tid]++; tok[r] = (j0+1) >> 1; rowidx[j0+1] = r;
            r = lcnt[v.z][tid]++; tok[r] = (j0+2) >> 1; rowidx[j0+2] = r;
            r = lcnt[v.w][tid]++; tok[r] = (j0+3) >> 1; rowidx[j0+3] = r;
        }
    }
}

// ---------------- transpose+convert: in [E][R][C] f32 -> out [E][C][R] bf16 ----------------
__global__ __launch_bounds__(256) void k_transpose(
    const float* __restrict__ in, __bf16* __restrict__ out, int R, int C)
{
    __shared__ float tile[64][65];
    const int e = blockIdx.z;
    const float* inp = in + (size_t)e * R * C;
    __bf16* outp = out + (size_t)e * R * C;
    const int r0 = blockIdx.x * 64, c0 = blockIdx.y * 64;
    const int c = threadIdx.x & 63, rr = threadIdx.x >> 6;
#pragma unroll
    for (int i = 0; i < 16; ++i) {
        int r = rr + i * 4;
        tile[r][c] = inp[(size_t)(r0 + r) * C + c0 + c];
    }
    __syncthreads();
#pragma unroll
    for (int i = 0; i < 16; ++i) {
        int cc = rr + i * 4;
        outp[(size_t)(c0 + cc) * R + r0 + c] = (__bf16)tile[c][cc];
    }
}

// ================= GEMMs: 128x128 tile, BK=64, row-XOR LDS swizzle =================
// LDS row-major [128][64]bf16 (128 B rows). 16B chunk c of row m stored at
// position c ^ (m&7): kills the row-stride-128B bank aliasing, and staging
// keeps global_load_lds's lane-ordered dest (lane l writes base + l*16).

// ---------------- GEMM1: h = relu(gather(x) @ W1[e] + b1[e]) -> hbuf ----------------
__global__ __launch_bounds__(256) void k_gemm1(
    const __bf16* __restrict__ xb, const __bf16* __restrict__ W1T,
    const float* __restrict__ b1, const int* __restrict__ tok,
    const int* __restrict__ mb2e, const int* __restrict__ mbrow0,
    const int* __restrict__ mbTot, __bf16* __restrict__ hbuf)
{
    const int id   = blockIdx.x;            // 0..2175, XCD-aware swizzle
    const int xcd  = id & 7;
    const int j    = id >> 3;
    const int nblk = j & 15;
    const int mb   = (j >> 4) * 8 + xcd;
    if (mb >= *mbTot) return;
    const int e    = mb2e[mb];
    const int row0 = mbrow0[mb];
    const int n0   = nblk * 128;

    __shared__ __align__(16) char smem[32768];   // A [0,16K), B [16K,32K)

    const int tid = threadIdx.x;
    const int w = tid >> 6, l = tid & 63;
    const int lrow  = l >> 3;                    // sub-row 0..7
    const int chunk = (l & 7) ^ lrow;            // swizzled global chunk

    const __bf16* Wb = W1T + (size_t)e * (size_t)(H_DIM * D_DIM);
    const __bf16* gA[4]; const __bf16* gB[4];
#pragma unroll
    for (int jj = 0; jj < 4; ++jj) {
        int rr = w*32 + jj*8 + lrow;             // 0..127
        gA[jj] = xb + (size_t)tok[row0 + rr] * D_DIM + chunk * 8;
        gB[jj] = Wb + (size_t)(n0 + rr) * D_DIM + chunk * 8;
    }
    char* ldsA = smem + w*4096 + l*16;
    char* ldsB = smem + 16384 + w*4096 + l*16;

    const int r = l & 15, q = l >> 4;
    const int wm = w & 1, wn = w >> 1;
    const int r7 = r & 7;

    f32x4 acc[4][4];
#pragma unroll
    for (int mi = 0; mi < 4; ++mi)
#pragma unroll
        for (int ni = 0; ni < 4; ++ni) acc[mi][ni] = (f32x4){0.f, 0.f, 0.f, 0.f};

    for (int k0 = 0; k0 < D_DIM; k0 += 64) {
#pragma unroll
        for (int jj = 0; jj < 4; ++jj) gload_lds16(gA[jj] + k0, ldsA + jj*1024);
#pragma unroll
        for (int jj = 0; jj < 4; ++jj) gload_lds16(gB[jj] + k0, ldsB + jj*1024);
        __syncthreads();

#pragma unroll
        for (int s = 0; s < 2; ++s) {
            const int cx = ((s*4 + q) ^ r7) * 16;
            bf16x8 av[4], bv[4];
#pragma unroll
            for (int mi = 0; mi < 4; ++mi)
                av[mi] = *(const bf16x8*)(smem + (wm*64 + mi*16 + r) * 128 + cx);
#pragma unroll
            for (int ni = 0; ni < 4; ++ni)
                bv[ni] = *(const bf16x8*)(smem + 16384 + (wn*64 + ni*16 + r) * 128 + cx);
#pragma unroll
            for (int mi = 0; mi < 4; ++mi)
#pragma unroll
                for (int ni = 0; ni < 4; ++ni)
                    acc[mi][ni] = __builtin_amdgcn_mfma_f32_16x16x32_bf16(av[mi], bv[ni], acc[mi][ni], 0, 0, 0);
        }
        __syncthreads();
    }

    const float* b1e = b1 + (size_t)e * H_DIM;
    float bb[4];
#pragma unroll
    for (int ni = 0; ni < 4; ++ni) bb[ni] = b1e[n0 + wn*64 + ni*16 + r];
#pragma unroll
    for (int mi = 0; mi < 4; ++mi)
#pragma unroll
        for (int reg = 0; reg < 4; ++reg) {
            int m = wm*64 + mi*16 + q*4 + reg;
            __bf16* hrow = hbuf + (size_t)(row0 + m) * H_DIM + n0 + wn*64;
#pragma unroll
            for (int ni = 0; ni < 4; ++ni) {
                float v = acc[mi][ni][reg] + bb[ni];
                hrow[ni*16 + r] = (__bf16)fmaxf(v, 0.f);
            }
        }
}

// ---------------- GEMM2: ybuf[row] = hbuf[row] @ W2[e] + b2[e] ----------------
__global__ __launch_bounds__(256) void k_gemm2(
    const __bf16* __restrict__ hbuf, const __bf16* __restrict__ W2T,
    const float* __restrict__ b2, const int* __restrict__ mb2e,
    const int* __restrict__ mbrow0, const int* __restrict__ mbTot,
    __bf16* __restrict__ ybuf)
{
    const int id   = blockIdx.x;            // 0..1087
    const int xcd  = id & 7;
    const int j    = id >> 3;
    const int nblk = j & 7;
    const int mb   = (j >> 3) * 8 + xcd;
    if (mb >= *mbTot) return;
    const int e    = mb2e[mb];
    const int row0 = mbrow0[mb];
    const int n0   = nblk * 128;

    __shared__ __align__(16) char smem[32768];

    const int tid = threadIdx.x;
    const int w = tid >> 6, l = tid & 63;
    const int lrow  = l >> 3;
    const int chunk = (l & 7) ^ lrow;

    const __bf16* Wb = W2T + (size_t)e * (size_t)(D_DIM * H_DIM);
    const __bf16* gA[4]; const __bf16* gB[4];
#pragma unroll
    for (int jj = 0; jj < 4; ++jj) {
        int rr = w*32 + jj*8 + lrow;
        gA[jj] = hbuf + (size_t)(row0 + rr) * H_DIM + chunk * 8;
        gB[jj] = Wb + (size_t)(n0 + rr) * H_DIM + chunk * 8;
    }
    char* ldsA = smem + w*4096 + l*16;
    char* ldsB = smem + 16384 + w*4096 + l*16;

    const int r = l & 15, q = l >> 4;
    const int wm = w & 1, wn = w >> 1;
    const int r7 = r & 7;

    f32x4 acc[4][4];
#pragma unroll
    for (int mi = 0; mi < 4; ++mi)
#pragma unroll
        for (int ni = 0; ni < 4; ++ni) acc[mi][ni] = (f32x4){0.f, 0.f, 0.f, 0.f};

    for (int k0 = 0; k0 < H_DIM; k0 += 64) {
#pragma unroll
        for (int jj = 0; jj < 4; ++jj) gload_lds16(gA[jj] + k0, ldsA + jj*1024);
#pragma unroll
        for (int jj = 0; jj < 4; ++jj) gload_lds16(gB[jj] + k0, ldsB + jj*1024);
        __syncthreads();

#pragma unroll
        for (int s = 0; s < 2; ++s) {
            const int cx = ((s*4 + q) ^ r7) * 16;
            bf16x8 av[4], bv[4];
#pragma unroll
            for (int mi = 0; mi < 4; ++mi)
                av[mi] = *(const bf16x8*)(smem + (wm*64 + mi*16 + r) * 128 + cx);
#pragma unroll
            for (int ni = 0; ni < 4; ++ni)
                bv[ni] = *(const bf16x8*)(smem + 16384 + (wn*64 + ni*16 + r) * 128 + cx);
#pragma unroll
            for (int mi = 0; mi < 4; ++mi)
#pragma unroll
                for (int ni = 0; ni < 4; ++ni)
                    acc[mi][ni] = __builtin_amdgcn_mfma_f32_16x16x32_bf16(av[mi], bv[ni], acc[mi][ni], 0, 0, 0);
        }
        __syncthreads();
    }

    const float* b2e = b2 + (size_t)e * D_DIM;
    float bb[4];
#pragma unroll
    for (int ni = 0; ni < 4; ++ni) bb[ni] = b2e[n0 + wn*64 + ni*16 + r];
#pragma unroll
    for (int mi = 0; mi < 4; ++mi)
#pragma unroll
        for (int reg = 0; reg < 4; ++reg) {
            int row = row0 + wm*64 + mi*16 + q*4 + reg;
            __bf16* yrow = ybuf + (size_t)row * D_DIM + n0 + wn*64;
#pragma unroll
            for (int ni = 0; ni < 4; ++ni)
                yrow[ni*16 + r] = (__bf16)(acc[mi][ni][reg] + bb[ni]);
        }
}

// ---------------- combine: out[t] = s0*y[r0] + s1*y[r1] ----------------
__global__ __launch_bounds__(256) void k_combine(
    const __bf16* __restrict__ ybuf, const int* __restrict__ rowidx,
    const float* __restrict__ topk_s, float* __restrict__ out)
{
    const int t = blockIdx.x;
    const int d0 = threadIdx.x * 4;
    const int r0 = rowidx[t*2+0], r1 = rowidx[t*2+1];
    const float s0 = topk_s[t*2+0], s1 = topk_s[t*2+1];
    bf16x4 y0 = *(const bf16x4*)(ybuf + (size_t)r0 * D_DIM + d0);
    bf16x4 y1 = *(const bf16x4*)(ybuf + (size_t)r1 * D_DIM + d0);
    float4 o;
    o.x = s0 * (float)y0[0] + s1 * (float)y1[0];
    o.y = s0 * (float)y0[1] + s1 * (float)y1[1];
    o.z = s0 * (float)y0[2] + s1 * (float)y1[2];
    o.w = s0 * (float)y0[3] + s1 * (float)y1[3];
    *(float4*)(out + (size_t)t * D_DIM + d0) = o;
}

extern "C" void kernel_launch(void* const* d_in, const int* in_sizes, int n_in,
                              void* d_out, int out_size, void* d_ws, size_t ws_size,
                              hipStream_t stream) {
    const float* x  = (const float*)d_in[0];
    const float* Wg = (const float*)d_in[1];
    const float* W1 = (const float*)d_in[2];
    const float* b1 = (const float*)d_in[3];
    const float* W2 = (const float*)d_in[4];
    const float* b2 = (const float*)d_in[5];
    float* out = (float*)d_out;
    char* ws = (char*)d_ws;

    int*   mbTot  = (int*)  (ws + OFF_MBTOT);
    int*   mb2e   = (int*)  (ws + OFF_MB2E);
    int*   mbrow0 = (int*)  (ws + OFF_MBROW0);
    int*   topk_e = (int*)  (ws + OFF_TOPKE);
    float* topk_s = (float*)(ws + OFF_TOPKS);
    int*   tok    = (int*)  (ws + OFF_TOK);
    int*   rowidx = (int*)  (ws + OFF_ROWIDX);
    __bf16* xb   = (__bf16*)(ws + OFF_XB);
    __bf16* W1T  = (__bf16*)(ws + OFF_W1T);
    __bf16* W2T  = (__bf16*)(ws + OFF_W2T);
    __bf16* hbuf = (__bf16*)(ws + OFF_HBUF);
    __bf16* ybuf = (__bf16*)(ws + OFF_YBUF);

    // zero tok (pad rows -> tok=0). rowidx/mb tables fully written by k_sort.
    hipMemsetAsync(ws + OFF_TOK, 0, MAX_ROWS * sizeof(int), stream);

    k_router_cvt<<<T_TOK/4, 256, 0, stream>>>(x, Wg, xb, topk_e, topk_s);
    k_sort      <<<1, 512, 0, stream>>>(topk_e, mbTot, mb2e, mbrow0, tok, rowidx);
    k_transpose <<<dim3(D_DIM/64, H_DIM/64, E_NUM), 256, 0, stream>>>(W1, W1T, D_DIM, H_DIM);
    k_transpose <<<dim3(H_DIM/64, D_DIM/64, E_NUM), 256, 0, stream>>>(W2, W2T, H_DIM, D_DIM);

    k_gemm1<<<MAX_MB * (H_DIM/128), 256, 0, stream>>>(xb, W1T, b1, tok, mb2e, mbrow0, mbTot, hbuf);
    k_gemm2<<<MAX_MB * (D_DIM/128), 256, 0, stream>>>(hbuf, W2T, b2, mb2e, mbrow0, mbTot, ybuf);
    k_combine<<<T_TOK, 256, 0, stream>>>(ybuf, rowidx, topk_s, out);
}

// Round 7
// 451.803 us; speedup vs baseline: 1.0022x; 1.0022x over previous
//
#include <hip/hip_runtime.h>
#include <hip/hip_bf16.h>

typedef __bf16 bf16x8 __attribute__((ext_vector_type(8)));
typedef __bf16 bf16x4 __attribute__((ext_vector_type(4)));
typedef float  f32x4  __attribute__((ext_vector_type(4)));

#define T_TOK    8192
#define D_DIM    1024
#define H_DIM    2048
#define E_NUM    8
#define MAX_MB   272      // 64-row blocks: sum 2*ceil(n_e/128) <= 272
#define MAX_ROWS 17408    // 136*128

// ---- workspace layout (bytes) ----
#define OFF_MBTOT   512
#define OFF_MB2E    1024            // 272 ints -> ends 2112
#define OFF_MBROW0  2560            // 272 ints -> ends 3648
#define OFF_TOPKE   4096            // 16384 ints  -> ends 69632
#define OFF_TOPKS   69632           // 16384 float -> ends 135168
#define OFF_TOK     135168          // 17408 ints  -> ends 204800
#define OFF_ROWIDX  204800          // 16384 ints  -> ends 270336
#define OFF_XB      (1u<<20)                    // 8192*1024*2  = 16 MiB
#define OFF_W1T     (18u*1024*1024)             // 8*2048*1024*2 = 32 MiB
#define OFF_W2T     (50u*1024*1024)             // 8*1024*2048*2 = 32 MiB
#define OFF_HBUF    (82u*1024*1024)             // 17408*2048*2  = 68 MiB
#define OFF_YBUF    OFF_XB                      // overlaid on xb+W1T (dead after gemm1)

__device__ __forceinline__ void gload_lds16(const void* g, void* l) {
    __builtin_amdgcn_global_load_lds(
        (const __attribute__((address_space(1))) void*)g,
        (__attribute__((address_space(3))) void*)l, 16, 0, 0);
}

// ---------------- fused router (+ fp32->bf16 convert of x) ----------------
// Wg staged in LDS as padded rows [1024][9] f32: lane-stride 9 floats ->
// conflict-free scalar reads (gcd(9,32)=1). No atomics anywhere.
__global__ __launch_bounds__(256) void k_router_cvt(
    const float* __restrict__ x, const float* __restrict__ Wg,
    __bf16* __restrict__ xb, int* __restrict__ topk_e, float* __restrict__ topk_s)
{
    __shared__ float wgP[D_DIM * 9];
    const int tid = threadIdx.x;
#pragma unroll
    for (int i = 0; i < 32; ++i) {
        int f = tid + i * 256;               // coalesced read of Wg[1024][8]
        wgP[(f >> 3) * 9 + (f & 7)] = Wg[f]; // 2-3 way store aliasing: free-ish
    }
    __syncthreads();

    const int wave = tid >> 6, lane = tid & 63;
    const int t = blockIdx.x * 4 + wave;
    const float* xr = x + (size_t)t * D_DIM;
    __bf16* xbr = xb + (size_t)t * D_DIM;

    float acc[E_NUM];
#pragma unroll
    for (int e = 0; e < E_NUM; ++e) acc[e] = 0.f;

#pragma unroll
    for (int j = 0; j < 16; ++j) {
        const int d = j * 64 + lane;
        const float xd = xr[d];
        const float* wr = &wgP[d * 9];
#pragma unroll
        for (int e = 0; e < E_NUM; ++e) acc[e] += xd * wr[e];
    }
    // fp32 -> bf16 convert of this token's row (x re-read, L1-hot)
#pragma unroll
    for (int j = 0; j < 4; ++j) {
        const int d0 = lane * 4 + j * 256;
        float4 xv = *(const float4*)(xr + d0);
        bf16x4 o = { (__bf16)xv.x, (__bf16)xv.y, (__bf16)xv.z, (__bf16)xv.w };
        *(bf16x4*)(xbr + d0) = o;
    }
#pragma unroll
    for (int off = 32; off >= 1; off >>= 1)
#pragma unroll
        for (int e = 0; e < E_NUM; ++e) acc[e] += __shfl_xor(acc[e], off, 64);

    if (lane == 0) {
        int e0 = 0; float v0 = acc[0];
#pragma unroll
        for (int e = 1; e < E_NUM; ++e) if (acc[e] > v0) { v0 = acc[e]; e0 = e; }
        int e1 = -1; float v1 = -1e30f;
#pragma unroll
        for (int e = 0; e < E_NUM; ++e) if (e != e0 && acc[e] > v1) { v1 = acc[e]; e1 = e; }
        float s0 = 1.f / (1.f + __expf(v1 - v0));  // renormalized top-2 softmax
        float s1 = 1.f - s0;
        topk_e[t*2+0] = e0; topk_e[t*2+1] = e1;
        topk_s[t*2+0] = s0; topk_s[t*2+1] = s1;
    }
}

// ---------------- single-block counting sort (LDS counters) + tok zero-init ----------------
#define SORT_T 256
__global__ __launch_bounds__(512) void k_sort(
    const int* __restrict__ topk_e,
    int* __restrict__ mbTot, int* __restrict__ mb2e, int* __restrict__ mbrow0,
    int* __restrict__ tok, int* __restrict__ rowidx)
{
    __shared__ int lcnt[E_NUM][SORT_T];
    __shared__ int base[E_NUM];
    __shared__ int etot[E_NUM];
    const int tid = threadIdx.x;

    // zero tok (pad rows must read tok=0); completes before phase-4 writes (barriers)
    for (int i = tid; i < MAX_ROWS; i += 512) tok[i] = 0;

    if (tid < SORT_T) {
#pragma unroll
        for (int e = 0; e < E_NUM; ++e) lcnt[e][tid] = 0;
    }
    __syncthreads();

    if (tid < SORT_T) {
        const int4* p = (const int4*)(topk_e + tid * 64);
#pragma unroll
        for (int i = 0; i < 16; ++i) {
            int4 v = p[i];
            lcnt[v.x][tid]++; lcnt[v.y][tid]++; lcnt[v.z][tid]++; lcnt[v.w][tid]++;
        }
    }
    __syncthreads();

    {   // wave w scans expert w's 256 thread-counts (exclusive)
        const int w = tid >> 6, l = tid & 63;
        int v0 = lcnt[w][l*4+0], v1 = lcnt[w][l*4+1], v2 = lcnt[w][l*4+2], v3 = lcnt[w][l*4+3];
        int s = v0 + v1 + v2 + v3;
        int inc = s;
#pragma unroll
        for (int off = 1; off < 64; off <<= 1) {
            int o = __shfl_up(inc, off, 64);
            if (l >= off) inc += o;
        }
        int exc = inc - s;
        lcnt[w][l*4+0] = exc;
        lcnt[w][l*4+1] = exc + v0;
        lcnt[w][l*4+2] = exc + v0 + v1;
        lcnt[w][l*4+3] = exc + v0 + v1 + v2;
        if (l == 63) etot[w] = inc;
    }
    __syncthreads();

    if (tid == 0) {   // 64-row M-block tables (row space stays 128-padded)
        int row = 0, mb = 0;
        for (int e = 0; e < E_NUM; ++e) {
            base[e] = row;
            int nb = (etot[e] + 127) >> 7;
            for (int b = 0; b < 2*nb; ++b) { mb2e[mb] = e; mbrow0[mb] = row + b*64; ++mb; }
            row += nb * 128;
        }
        mbTot[0] = mb;
    }
    __syncthreads();

    if (tid < SORT_T) {
#pragma unroll
        for (int e = 0; e < E_NUM; ++e) lcnt[e][tid] += base[e];
        const int4* p = (const int4*)(topk_e + tid * 64);
#pragma unroll
        for (int i = 0; i < 16; ++i) {
            int4 v = p[i];
            int j0 = tid * 64 + i * 4;
            int r;
            r = lcnt[v.x][tid]++; tok[r] = (j0+0) >> 1; rowidx[j0+0] = r;
            r = lcnt[v.y][tid]++; tok[r] = (j0+1) >> 1; rowidx[j0+1] = r;
            r = lcnt[v.z][tid]++; tok[r] = (j0+2) >> 1; rowidx[j0+2] = r;
            r = lcnt[v.w][tid]++; tok[r] = (j0+3) >> 1; rowidx[j0+3] = r;
        }
    }
}

// ---------------- fused transpose+convert for W1 and W2 (one launch) ----------------
// W1 [E][1024][2048] -> W1T [E][2048][1024]; W2 [E][2048][1024] -> W2T [E][1024][2048]
__global__ __launch_bounds__(256) void k_transpose_all(
    const float* __restrict__ W1, __bf16* __restrict__ W1T,
    const float* __restrict__ W2, __bf16* __restrict__ W2T)
{
    __shared__ float tile[64][65];
    int id = blockIdx.x;                 // 0..8191
    const float* inp; __bf16* outp; int R, C, r0, c0;
    if (id < 4096) {
        int e = id >> 9, tl = id & 511;  // 16 x 32 tiles
        R = D_DIM; C = H_DIM;
        r0 = (tl & 15) * 64; c0 = (tl >> 4) * 64;
        inp = W1 + (size_t)e * R * C; outp = W1T + (size_t)e * R * C;
    } else {
        id -= 4096;
        int e = id >> 9, tl = id & 511;  // 32 x 16 tiles
        R = H_DIM; C = D_DIM;
        r0 = (tl & 31) * 64; c0 = (tl >> 5) * 64;
        inp = W2 + (size_t)e * R * C; outp = W2T + (size_t)e * R * C;
    }
    const int c = threadIdx.x & 63, rr = threadIdx.x >> 6;
#pragma unroll
    for (int i = 0; i < 16; ++i) {
        int r = rr + i * 4;
        tile[r][c] = inp[(size_t)(r0 + r) * C + c0 + c];
    }
    __syncthreads();
#pragma unroll
    for (int i = 0; i < 16; ++i) {
        int cc = rr + i * 4;
        outp[(size_t)(c0 + cc) * R + r0 + c] = (__bf16)tile[c][cc];
    }
}

// ================= GEMMs: 64x128 tile, 2 waves, BK=64, row-XOR swizzle =================
// LDS rows 128B ([64|128][64]bf16); 16B chunk c of row m at pos c^(m&7).
// Phase-wise (16-lane) bank pattern verified conflict-free (R4/R6: counter=0).

// ---------------- GEMM1: h = relu(gather(x) @ W1[e] + b1[e]) -> hbuf ----------------
__global__ __launch_bounds__(128) void k_gemm1(
    const __bf16* __restrict__ xb, const __bf16* __restrict__ W1T,
    const float* __restrict__ b1, const int* __restrict__ tok,
    const int* __restrict__ mb2e, const int* __restrict__ mbrow0,
    const int* __restrict__ mbTot, __bf16* __restrict__ hbuf)
{
    const int id   = blockIdx.x;            // 272*16 = 4352, XCD-aware swizzle
    const int xcd  = id & 7;
    const int j    = id >> 3;
    const int nblk = j & 15;
    const int mb   = (j >> 4) * 8 + xcd;
    if (mb >= *mbTot) return;
    const int e    = mb2e[mb];
    const int row0 = mbrow0[mb];
    const int n0   = nblk * 128;

    __shared__ __align__(16) char smem[24576];   // A [0,8K), B [8K,24K)

    const int tid = threadIdx.x;
    const int w = tid >> 6, l = tid & 63;
    const int lrow  = l >> 3;
    const int chunk = (l & 7) ^ lrow;

    const __bf16* Wb = W1T + (size_t)e * (size_t)(H_DIM * D_DIM);
    const __bf16* gA[2]; const __bf16* gB[4];
#pragma unroll
    for (int jj = 0; jj < 2; ++jj) {
        int rr = jj*16 + w*8 + lrow;             // A rows 0..31 (+32 via second pair)
        gA[jj] = xb + (size_t)tok[row0 + rr] * D_DIM + chunk * 8;
    }
    const __bf16* gA2[2];
#pragma unroll
    for (int jj = 0; jj < 2; ++jj) {
        int rr = 32 + jj*16 + w*8 + lrow;        // A rows 32..63
        gA2[jj] = xb + (size_t)tok[row0 + rr] * D_DIM + chunk * 8;
    }
#pragma unroll
    for (int jj = 0; jj < 4; ++jj) {
        int rr = jj*16 + w*8 + lrow;             // B rows 0..63 (x2 halves)
        gB[jj] = Wb + (size_t)(n0 + rr) * D_DIM + chunk * 8;
    }
    const __bf16* gB2[4];
#pragma unroll
    for (int jj = 0; jj < 4; ++jj) {
        int rr = 64 + jj*16 + w*8 + lrow;        // B rows 64..127
        gB2[jj] = Wb + (size_t)(n0 + rr) * D_DIM + chunk * 8;
    }
    char* ldsA = smem + w*1024 + l*16;
    char* ldsB = smem + 8192 + w*1024 + l*16;

    const int r = l & 15, q = l >> 4;
    const int r7 = r & 7;

    f32x4 acc[4][4];
#pragma unroll
    for (int mi = 0; mi < 4; ++mi)
#pragma unroll
        for (int ni = 0; ni < 4; ++ni) acc[mi][ni] = (f32x4){0.f, 0.f, 0.f, 0.f};

    for (int k0 = 0; k0 < D_DIM; k0 += 64) {
#pragma unroll
        for (int jj = 0; jj < 2; ++jj) gload_lds16(gA[jj]  + k0, ldsA + jj*2048);
#pragma unroll
        for (int jj = 0; jj < 2; ++jj) gload_lds16(gA2[jj] + k0, ldsA + 4096 + jj*2048);
#pragma unroll
        for (int jj = 0; jj < 4; ++jj) gload_lds16(gB[jj]  + k0, ldsB + jj*2048);
#pragma unroll
        for (int jj = 0; jj < 4; ++jj) gload_lds16(gB2[jj] + k0, ldsB + 8192 + jj*2048);
        __syncthreads();

#pragma unroll
        for (int s = 0; s < 2; ++s) {
            const int cx = ((s*4 + q) ^ r7) * 16;
            bf16x8 av[4], bv[4];
#pragma unroll
            for (int mi = 0; mi < 4; ++mi)
                av[mi] = *(const bf16x8*)(smem + (mi*16 + r) * 128 + cx);
#pragma unroll
            for (int ni = 0; ni < 4; ++ni)
                bv[ni] = *(const bf16x8*)(smem + 8192 + (w*64 + ni*16 + r) * 128 + cx);
#pragma unroll
            for (int mi = 0; mi < 4; ++mi)
#pragma unroll
                for (int ni = 0; ni < 4; ++ni)
                    acc[mi][ni] = __builtin_amdgcn_mfma_f32_16x16x32_bf16(av[mi], bv[ni], acc[mi][ni], 0, 0, 0);
        }
        __syncthreads();
    }

    const float* b1e = b1 + (size_t)e * H_DIM;
    float bb[4];
#pragma unroll
    for (int ni = 0; ni < 4; ++ni) bb[ni] = b1e[n0 + w*64 + ni*16 + r];
#pragma unroll
    for (int mi = 0; mi < 4; ++mi)
#pragma unroll
        for (int reg = 0; reg < 4; ++reg) {
            int m = mi*16 + q*4 + reg;
            __bf16* hrow = hbuf + (size_t)(row0 + m) * H_DIM + n0 + w*64;
#pragma unroll
            for (int ni = 0; ni < 4; ++ni) {
                float v = acc[mi][ni][reg] + bb[ni];
                hrow[ni*16 + r] = (__bf16)fmaxf(v, 0.f);
            }
        }
}

// ---------------- GEMM2: ybuf[row] = hbuf[row] @ W2[e] + b2[e] ----------------
__global__ __launch_bounds__(128) void k_gemm2(
    const __bf16* __restrict__ hbuf, const __bf16* __restrict__ W2T,
    const float* __restrict__ b2, const int* __restrict__ mb2e,
    const int* __restrict__ mbrow0, const int* __restrict__ mbTot,
    __bf16* __restrict__ ybuf)
{
    const int id   = blockIdx.x;            // 272*8 = 2176
    const int xcd  = id & 7;
    const int j    = id >> 3;
    const int nblk = j & 7;
    const int mb   = (j >> 3) * 8 + xcd;
    if (mb >= *mbTot) return;
    const int e    = mb2e[mb];
    const int row0 = mbrow0[mb];
    const int n0   = nblk * 128;

    __shared__ __align__(16) char smem[24576];

    const int tid = threadIdx.x;
    const int w = tid >> 6, l = tid & 63;
    const int lrow  = l >> 3;
    const int chunk = (l & 7) ^ lrow;

    const __bf16* Wb = W2T + (size_t)e * (size_t)(D_DIM * H_DIM);
    const __bf16* gA[4]; const __bf16* gB[4]; const __bf16* gB2[4];
#pragma unroll
    for (int jj = 0; jj < 4; ++jj) {
        int rr = jj*16 + w*8 + lrow;
        gA[jj]  = hbuf + (size_t)(row0 + rr) * H_DIM + chunk * 8;     // A rows 0..63
        gB[jj]  = Wb + (size_t)(n0 + rr) * H_DIM + chunk * 8;          // B rows 0..63
        gB2[jj] = Wb + (size_t)(n0 + 64 + rr) * H_DIM + chunk * 8;     // B rows 64..127
    }
    char* ldsA = smem + w*1024 + l*16;
    char* ldsB = smem + 8192 + w*1024 + l*16;

    const int r = l & 15, q = l >> 4;
    const int r7 = r & 7;

    f32x4 acc[4][4];
#pragma unroll
    for (int mi = 0; mi < 4; ++mi)
#pragma unroll
        for (int ni = 0; ni < 4; ++ni) acc[mi][ni] = (f32x4){0.f, 0.f, 0.f, 0.f};

    for (int k0 = 0; k0 < H_DIM; k0 += 64) {
#pragma unroll
        for (int jj = 0; jj < 2; ++jj) gload_lds16(gA[jj]   + k0, ldsA + jj*2048);
#pragma unroll
        for (int jj = 0; jj < 2; ++jj) gload_lds16(gA[2+jj] + k0, ldsA + 4096 + jj*2048);
#pragma unroll
        for (int jj = 0; jj < 4; ++jj) gload_lds16(gB[jj]  + k0, ldsB + jj*2048);
#pragma unroll
        for (int jj = 0; jj < 4; ++jj) gload_lds16(gB2[jj] + k0, ldsB + 8192 + jj*2048);
        __syncthreads();

#pragma unroll
        for (int s = 0; s < 2; ++s) {
            const int cx = ((s*4 + q) ^ r7) * 16;
            bf16x8 av[4], bv[4];
#pragma unroll
            for (int mi = 0; mi < 4; ++mi)
                av[mi] = *(const bf16x8*)(smem + (mi*16 + r) * 128 + cx);
#pragma unroll
            for (int ni = 0; ni < 4; ++ni)
                bv[ni] = *(const bf16x8*)(smem + 8192 + (w*64 + ni*16 + r) * 128 + cx);
#pragma unroll
            for (int mi = 0; mi < 4; ++mi)
#pragma unroll
                for (int ni = 0; ni < 4; ++ni)
                    acc[mi][ni] = __builtin_amdgcn_mfma_f32_16x16x32_bf16(av[mi], bv[ni], acc[mi][ni], 0, 0, 0);
        }
        __syncthreads();
    }

    const float* b2e = b2 + (size_t)e * D_DIM;
    float bb[4];
#pragma unroll
    for (int ni = 0; ni < 4; ++ni) bb[ni] = b2e[n0 + w*64 + ni*16 + r];
#pragma unroll
    for (int mi = 0; mi < 4; ++mi)
#pragma unroll
        for (int reg = 0; reg < 4; ++reg) {
            int row = row0 + mi*16 + q*4 + reg;
            __bf16* yrow = ybuf + (size_t)row * D_DIM + n0 + w*64;
#pragma unroll
            for (int ni = 0; ni < 4; ++ni)
                yrow[ni*16 + r] = (__bf16)(acc[mi][ni][reg] + bb[ni]);
        }
}

// ---------------- combine: out[t] = s0*y[r0] + s1*y[r1] ----------------
__global__ __launch_bounds__(256) void k_combine(
    const __bf16* __restrict__ ybuf, const int* __restrict__ rowidx,
    const float* __restrict__ topk_s, float* __restrict__ out)
{
    const int t = blockIdx.x;
    const int d0 = threadIdx.x * 4;
    const int r0 = rowidx[t*2+0], r1 = rowidx[t*2+1];
    const float s0 = topk_s[t*2+0], s1 = topk_s[t*2+1];
    bf16x4 y0 = *(const bf16x4*)(ybuf + (size_t)r0 * D_DIM + d0);
    bf16x4 y1 = *(const bf16x4*)(ybuf + (size_t)r1 * D_DIM + d0);
    float4 o;
    o.x = s0 * (float)y0[0] + s1 * (float)y1[0];
    o.y = s0 * (float)y0[1] + s1 * (float)y1[1];
    o.z = s0 * (float)y0[2] + s1 * (float)y1[2];
    o.w = s0 * (float)y0[3] + s1 * (float)y1[3];
    *(float4*)(out + (size_t)t * D_DIM + d0) = o;
}

extern "C" void kernel_launch(void* const* d_in, const int* in_sizes, int n_in,
                              void* d_out, int out_size, void* d_ws, size_t ws_size,
                              hipStream_t stream) {
    const float* x  = (const float*)d_in[0];
    const float* Wg = (const float*)d_in[1];
    const float* W1 = (const float*)d_in[2];
    const float* b1 = (const float*)d_in[3];
    const float* W2 = (const float*)d_in[4];
    const float* b2 = (const float*)d_in[5];
    float* out = (float*)d_out;
    char* ws = (char*)d_ws;

    int*   mbTot  = (int*)  (ws + OFF_MBTOT);
    int*   mb2e   = (int*)  (ws + OFF_MB2E);
    int*   mbrow0 = (int*)  (ws + OFF_MBROW0);
    int*   topk_e = (int*)  (ws + OFF_TOPKE);
    float* topk_s = (float*)(ws + OFF_TOPKS);
    int*   tok    = (int*)  (ws + OFF_TOK);
    int*   rowidx = (int*)  (ws + OFF_ROWIDX);
    __bf16* xb   = (__bf16*)(ws + OFF_XB);
    __bf16* W1T  = (__bf16*)(ws + OFF_W1T);
    __bf16* W2T  = (__bf16*)(ws + OFF_W2T);
    __bf16* hbuf = (__bf16*)(ws + OFF_HBUF);
    __bf16* ybuf = (__bf16*)(ws + OFF_YBUF);

    k_router_cvt  <<<T_TOK/4, 256, 0, stream>>>(x, Wg, xb, topk_e, topk_s);
    k_sort        <<<1, 512, 0, stream>>>(topk_e, mbTot, mb2e, mbrow0, tok, rowidx);
    k_transpose_all<<<8192, 256, 0, stream>>>(W1, W1T, W2, W2T);

    k_gemm1<<<MAX_MB * (H_DIM/128), 128, 0, stream>>>(xb, W1T, b1, tok, mb2e, mbrow0, mbTot, hbuf);
    k_gemm2<<<MAX_MB * (D_DIM/128), 128, 0, stream>>>(hbuf, W2T, b2, mb2e, mbrow0, mbTot, ybuf);
    k_combine<<<T_TOK, 256, 0, stream>>>(ybuf, rowidx, topk_s, out);
}